// Round 1
// baseline (5108.726 us; speedup 1.0000x reference)
//
#include <hip/hip_runtime.h>
#include <math.h>

// ---------------------------------------------------------------------------
// AGNN stack: h=relu(x@W1+b1); 32x AGNNConv(beta=1); log_softmax(h@W2+b2)
// N=100000, F=512, H=32, C=40, E=3200000 (+N self loops)
// Strategy: build CSR by dst once per launch, then wave-per-node online-softmax
// attention layers with fused next-layer inv-norm epilogue.
// ---------------------------------------------------------------------------

#define HDIM 32

// edge storage may be int32 or int64 (reference uses int64; harness doc says
// int32). Detect on device: int64 => high words of first 64 entries all zero.
static __device__ __forceinline__ int eread(const int* __restrict__ e, int i64, long long idx) {
    return i64 ? e[2 * idx] : e[idx];
}

__global__ void k_flag(const int* __restrict__ e, int* __restrict__ flag) {
    if (blockIdx.x == 0 && threadIdx.x == 0) {
        int z = 0;
        for (int k = 0; k < 64; ++k) z |= e[2 * k + 1];
        *flag = (z == 0) ? 1 : 0;
    }
}

__global__ void k_zero(int* __restrict__ deg, int N) {
    int i = blockIdx.x * blockDim.x + threadIdx.x;
    if (i < N) deg[i] = 0;
}

__global__ void k_count(const int* __restrict__ e, const int* __restrict__ flag,
                        int* __restrict__ deg, long long E, int N) {
    long long m = (long long)blockIdx.x * blockDim.x + threadIdx.x;
    long long M = E + N;
    if (m >= M) return;
    int i64 = *flag;
    int d = (m < E) ? eread(e, i64, E + m) : (int)(m - E);
    atomicAdd(&deg[d], 1);
}

// two-level exclusive scan: scan1 (1024 elems/block) -> scan2 (block sums) -> scan3 (add)
__global__ void k_scan1(const int* __restrict__ deg, int* __restrict__ rp,
                        int* __restrict__ bsums, int N) {
    __shared__ int lds[256];
    int t = threadIdx.x;
    int base = blockIdx.x * 1024 + t * 4;
    int v[4];
#pragma unroll
    for (int d = 0; d < 4; ++d) v[d] = (base + d < N) ? deg[base + d] : 0;
    int tsum = v[0] + v[1] + v[2] + v[3];
    lds[t] = tsum;
    __syncthreads();
    int acc = tsum;
    for (int sh = 1; sh < 256; sh <<= 1) {
        int x = (t >= sh) ? lds[t - sh] : 0;
        __syncthreads();
        acc += x;
        lds[t] = acc;
        __syncthreads();
    }
    if (t == 255) bsums[blockIdx.x] = acc;
    int run = acc - tsum;  // exclusive prefix of this thread's 4
#pragma unroll
    for (int d = 0; d < 4; ++d) {
        if (base + d < N) rp[base + d] = run;
        run += v[d];
    }
}

__global__ void k_scan2(const int* __restrict__ bsums, int* __restrict__ boffs,
                        int* __restrict__ rp, int nb, int N) {
    __shared__ int lds[128];
    int t = threadIdx.x;
    int v = (t < nb) ? bsums[t] : 0;
    lds[t] = v;
    __syncthreads();
    int acc = v;
    for (int sh = 1; sh < 128; sh <<= 1) {
        int x = (t >= sh) ? lds[t - sh] : 0;
        __syncthreads();
        acc += x;
        lds[t] = acc;
        __syncthreads();
    }
    if (t < nb) boffs[t] = acc - v;
    if (t == nb - 1) rp[N] = acc;
}

__global__ void k_scan3(int* __restrict__ rp, int* __restrict__ cursor,
                        const int* __restrict__ boffs, int N) {
    int i = blockIdx.x * blockDim.x + threadIdx.x;
    if (i < N) {
        int v = rp[i] + boffs[i >> 10];
        rp[i] = v;
        cursor[i] = v;
    }
}

__global__ void k_scatter(const int* __restrict__ e, const int* __restrict__ flag,
                          int* __restrict__ cursor, int* __restrict__ col,
                          long long E, int N) {
    long long m = (long long)blockIdx.x * blockDim.x + threadIdx.x;
    long long M = E + N;
    if (m >= M) return;
    int i64 = *flag;
    int s, d;
    if (m < E) { s = eread(e, i64, m); d = eread(e, i64, E + m); }
    else { s = d = (int)(m - E); }
    int pos = atomicAdd(&cursor[d], 1);
    col[pos] = s;
}

// h = relu(x @ W1 + b1), fused inv_norm epilogue. block=(32,8), 32 rows/block.
__launch_bounds__(256) __global__
void k_gemm1(const float* __restrict__ x, const float* __restrict__ W1,
             const float* __restrict__ b1, float* __restrict__ h,
             float* __restrict__ invn, int N) {
    __shared__ float sW[512 * 32];  // 64 KiB
    int t = threadIdx.y * 32 + threadIdx.x;
    for (int i = t; i < 512 * 32; i += 256) sW[i] = W1[i];
    __syncthreads();
    int c = threadIdx.x;
    int r0 = blockIdx.x * 32 + threadIdx.y;  // rows r0 + 8*m
    float bias = b1[c];
    float acc[4];
    size_t roff[4];
    bool rv[4];
#pragma unroll
    for (int m = 0; m < 4; ++m) {
        int r = r0 + 8 * m;
        rv[m] = r < N;
        roff[m] = rv[m] ? (size_t)r * 512 : 0;
        acc[m] = bias;
    }
    for (int k4 = 0; k4 < 128; ++k4) {
        float w0 = sW[(4 * k4 + 0) * 32 + c];
        float w1 = sW[(4 * k4 + 1) * 32 + c];
        float w2 = sW[(4 * k4 + 2) * 32 + c];
        float w3 = sW[(4 * k4 + 3) * 32 + c];
#pragma unroll
        for (int m = 0; m < 4; ++m) {
            float4 xv = *(const float4*)(x + roff[m] + 4 * k4);
            acc[m] = fmaf(xv.x, w0, acc[m]);
            acc[m] = fmaf(xv.y, w1, acc[m]);
            acc[m] = fmaf(xv.z, w2, acc[m]);
            acc[m] = fmaf(xv.w, w3, acc[m]);
        }
    }
#pragma unroll
    for (int m = 0; m < 4; ++m) {
        int r = r0 + 8 * m;
        float hv = fmaxf(acc[m], 0.0f);
        float ss = hv * hv;
#pragma unroll
        for (int mask = 16; mask >= 1; mask >>= 1) ss += __shfl_xor(ss, mask);
        if (rv[m]) {
            h[(size_t)r * HDIM + c] = hv;
            if (c == 0) invn[r] = 1.0f / fmaxf(sqrtf(ss), 1e-12f);
        }
    }
}

// One wave per node. Online softmax over incoming edges; fused epilogue
// computes inv_norm of the produced row for the next layer.
__launch_bounds__(256) __global__
void k_agnn(const float* __restrict__ h_in, const float* __restrict__ inv_in,
            float* __restrict__ h_out, float* __restrict__ inv_out,
            const int* __restrict__ rp, const int* __restrict__ col, int N) {
    int wave = threadIdx.x >> 6;
    int lane = threadIdx.x & 63;
    int i = blockIdx.x * 4 + wave;
    if (i >= N) return;
    int beg = rp[i];
    int deg = rp[i + 1] - beg;
    float inv_i = inv_in[i];
    float hi[HDIM];
    {
        const float4* hp = (const float4*)(h_in + (size_t)i * HDIM);
#pragma unroll
        for (int c4 = 0; c4 < 8; ++c4) {
            float4 v = hp[c4];
            hi[4 * c4 + 0] = v.x; hi[4 * c4 + 1] = v.y;
            hi[4 * c4 + 2] = v.z; hi[4 * c4 + 3] = v.w;
        }
    }
    float m_run = -INFINITY, s_run = 0.0f;
    float4 acc = make_float4(0.f, 0.f, 0.f, 0.f);
    int g = lane & 7, joff = lane >> 3;
    for (int b = 0; b < deg; b += 64) {
        int idx = b + lane;
        bool valid = idx < deg;
        int src = valid ? col[beg + idx] : 0;
        // phase 1: lane-per-edge cosine attention logit
        float dot = 0.0f;
        const float4* hs = (const float4*)(h_in + (size_t)src * HDIM);
#pragma unroll
        for (int c4 = 0; c4 < 8; ++c4) {
            float4 v = hs[c4];
            dot = fmaf(v.x, hi[4 * c4 + 0], dot);
            dot = fmaf(v.y, hi[4 * c4 + 1], dot);
            dot = fmaf(v.z, hi[4 * c4 + 2], dot);
            dot = fmaf(v.w, hi[4 * c4 + 3], dot);
        }
        float alpha = valid ? dot * inv_i * inv_in[src] : -INFINITY;
        float mc = alpha;
#pragma unroll
        for (int mask = 32; mask >= 1; mask >>= 1) mc = fmaxf(mc, __shfl_xor(mc, mask));
        float m_new = fmaxf(m_run, mc);
        float scale = __expf(m_run - m_new);  // 0 on first chunk (-inf)
        float e = valid ? __expf(alpha - m_new) : 0.0f;
        float sc = e;
#pragma unroll
        for (int mask = 32; mask >= 1; mask >>= 1) sc += __shfl_xor(sc, mask);
        s_run = s_run * scale + sc;
        m_run = m_new;
        acc.x *= scale; acc.y *= scale; acc.z *= scale; acc.w *= scale;
        // phase 2: 8 edges x (8 lanes x float4), coalesced row gathers
        int jlim = min(64, deg - b);
        for (int j = 0; j < jlim; j += 8) {
            int sl = j + joff;
            float ej = __shfl(e, sl);
            int sj = __shfl(src, sl);
            float4 v = *(const float4*)(h_in + (size_t)sj * HDIM + 4 * g);
            acc.x = fmaf(ej, v.x, acc.x);
            acc.y = fmaf(ej, v.y, acc.y);
            acc.z = fmaf(ej, v.z, acc.z);
            acc.w = fmaf(ej, v.w, acc.w);
        }
    }
    float invs = 1.0f / s_run;
    acc.x *= invs; acc.y *= invs; acc.z *= invs; acc.w *= invs;
#pragma unroll
    for (int mask = 8; mask <= 32; mask <<= 1) {
        acc.x += __shfl_xor(acc.x, mask);
        acc.y += __shfl_xor(acc.y, mask);
        acc.z += __shfl_xor(acc.z, mask);
        acc.w += __shfl_xor(acc.w, mask);
    }
    if (lane < 8) {
        *(float4*)(h_out + (size_t)i * HDIM + 4 * lane) = acc;
        float ss = acc.x * acc.x + acc.y * acc.y + acc.z * acc.z + acc.w * acc.w;
        ss += __shfl_xor(ss, 1);
        ss += __shfl_xor(ss, 2);
        ss += __shfl_xor(ss, 4);
        if (lane == 0) inv_out[i] = 1.0f / fmaxf(sqrtf(ss), 1e-12f);
    }
}

// logits = h @ W2 + b2 ; out = log_softmax(logits). One wave per node.
__launch_bounds__(256) __global__
void k_gemm2(const float* __restrict__ h, const float* __restrict__ W2,
             const float* __restrict__ b2, float* __restrict__ out, int N) {
    int wave = threadIdx.x >> 6;
    int lane = threadIdx.x & 63;
    int i = blockIdx.x * 4 + wave;
    if (i >= N) return;
    bool act = lane < 40;
    float acc = act ? b2[lane] : 0.0f;
    const float* hr = h + (size_t)i * HDIM;
#pragma unroll
    for (int k = 0; k < HDIM; ++k) {
        float hk = hr[k];
        float w = act ? W2[k * 40 + lane] : 0.0f;
        acc = fmaf(hk, w, acc);
    }
    float logit = act ? acc : -INFINITY;
    float m = logit;
#pragma unroll
    for (int mask = 32; mask >= 1; mask >>= 1) m = fmaxf(m, __shfl_xor(m, mask));
    float e = act ? __expf(logit - m) : 0.0f;
    float s = e;
#pragma unroll
    for (int mask = 32; mask >= 1; mask >>= 1) s += __shfl_xor(s, mask);
    float res = logit - m - __logf(s);
    if (act) out[(size_t)i * 40 + lane] = res;
}

extern "C" void kernel_launch(void* const* d_in, const int* in_sizes, int n_in,
                              void* d_out, int out_size, void* d_ws, size_t ws_size,
                              hipStream_t stream) {
    const float* x  = (const float*)d_in[0];
    const int*   e  = (const int*)d_in[1];
    const float* W1 = (const float*)d_in[2];
    const float* b1 = (const float*)d_in[3];
    const float* W2 = (const float*)d_in[4];
    const float* b2 = (const float*)d_in[5];
    float* out = (float*)d_out;

    const long long E = (long long)in_sizes[1] / 2;
    const int N = in_sizes[0] / 512;  // F_in = 512
    const long long M = E + N;

    char* w = (char*)d_ws;
    auto alloc = [&](size_t bytes) -> void* {
        void* p = (void*)w;
        w += (bytes + 255) & ~(size_t)255;
        return p;
    };
    int* flag    = (int*)alloc(4);
    int* deg     = (int*)alloc((size_t)N * 4);
    int* rp      = (int*)alloc(((size_t)N + 1) * 4);
    int* cursor  = (int*)alloc((size_t)N * 4);
    int* bsums   = (int*)alloc(1024);
    int* boffs   = (int*)alloc(1024);
    int* col     = (int*)alloc((size_t)M * 4);
    float* hA    = (float*)alloc((size_t)N * HDIM * 4);
    float* hB    = (float*)alloc((size_t)N * HDIM * 4);
    float* invA  = (float*)alloc((size_t)N * 4);
    float* invB  = (float*)alloc((size_t)N * 4);
    if ((size_t)(w - (char*)d_ws) > ws_size) return;  // workspace too small

    k_flag<<<1, 64, 0, stream>>>(e, flag);
    k_zero<<<(N + 255) / 256, 256, 0, stream>>>(deg, N);
    k_count<<<(int)((M + 255) / 256), 256, 0, stream>>>(e, flag, deg, E, N);
    int nb = (N + 1023) / 1024;  // 98 <= 128
    k_scan1<<<nb, 256, 0, stream>>>(deg, rp, bsums, N);
    k_scan2<<<1, 128, 0, stream>>>(bsums, boffs, rp, nb, N);
    k_scan3<<<(N + 255) / 256, 256, 0, stream>>>(rp, cursor, boffs, N);
    k_scatter<<<(int)((M + 255) / 256), 256, 0, stream>>>(e, flag, cursor, col, E, N);

    k_gemm1<<<(N + 31) / 32, dim3(32, 8), 0, stream>>>(x, W1, b1, hA, invA, N);

    float *hin = hA, *hout = hB, *iin = invA, *iout = invB;
    for (int l = 0; l < 32; ++l) {
        k_agnn<<<(N + 3) / 4, 256, 0, stream>>>(hin, iin, hout, iout, rp, col, N);
        float* t;
        t = hin; hin = hout; hout = t;
        t = iin; iin = iout; iout = t;
    }
    k_gemm2<<<(N + 3) / 4, 256, 0, stream>>>(hin, W2, b2, out, N);
}

// Round 2
// 4770.814 us; speedup vs baseline: 1.0708x; 1.0708x over previous
//
#include <hip/hip_runtime.h>
#include <math.h>

// ---------------------------------------------------------------------------
// AGNN stack: h=relu(x@W1+b1); 32x AGNNConv(beta=1); log_softmax(h@W2+b2)
// N=100000, F=512, H=32, C=40, E=3200000 (+N self loops)
// R2: k_agnn single-gather via wave-private LDS transpose (halves L2/LLC
//     traffic); k_gemm1 no-LDS broadcast-W with 8 rows/thread (occupancy fix).
// ---------------------------------------------------------------------------

#define HDIM 32
#define LROW 36  // LDS row stride in floats: conflict-free b128 write+read

static __device__ __forceinline__ int eread(const int* __restrict__ e, int i64, long long idx) {
    return i64 ? e[2 * idx] : e[idx];
}

__global__ void k_flag(const int* __restrict__ e, int* __restrict__ flag) {
    if (blockIdx.x == 0 && threadIdx.x == 0) {
        int z = 0;
        for (int k = 0; k < 64; ++k) z |= e[2 * k + 1];
        *flag = (z == 0) ? 1 : 0;
    }
}

__global__ void k_zero(int* __restrict__ deg, int N) {
    int i = blockIdx.x * blockDim.x + threadIdx.x;
    if (i < N) deg[i] = 0;
}

__global__ void k_count(const int* __restrict__ e, const int* __restrict__ flag,
                        int* __restrict__ deg, long long E, int N) {
    long long m = (long long)blockIdx.x * blockDim.x + threadIdx.x;
    long long M = E + N;
    if (m >= M) return;
    int i64 = *flag;
    int d = (m < E) ? eread(e, i64, E + m) : (int)(m - E);
    atomicAdd(&deg[d], 1);
}

__global__ void k_scan1(const int* __restrict__ deg, int* __restrict__ rp,
                        int* __restrict__ bsums, int N) {
    __shared__ int lds[256];
    int t = threadIdx.x;
    int base = blockIdx.x * 1024 + t * 4;
    int v[4];
#pragma unroll
    for (int d = 0; d < 4; ++d) v[d] = (base + d < N) ? deg[base + d] : 0;
    int tsum = v[0] + v[1] + v[2] + v[3];
    lds[t] = tsum;
    __syncthreads();
    int acc = tsum;
    for (int sh = 1; sh < 256; sh <<= 1) {
        int x = (t >= sh) ? lds[t - sh] : 0;
        __syncthreads();
        acc += x;
        lds[t] = acc;
        __syncthreads();
    }
    if (t == 255) bsums[blockIdx.x] = acc;
    int run = acc - tsum;
#pragma unroll
    for (int d = 0; d < 4; ++d) {
        if (base + d < N) rp[base + d] = run;
        run += v[d];
    }
}

__global__ void k_scan2(const int* __restrict__ bsums, int* __restrict__ boffs,
                        int* __restrict__ rp, int nb, int N) {
    __shared__ int lds[128];
    int t = threadIdx.x;
    int v = (t < nb) ? bsums[t] : 0;
    lds[t] = v;
    __syncthreads();
    int acc = v;
    for (int sh = 1; sh < 128; sh <<= 1) {
        int x = (t >= sh) ? lds[t - sh] : 0;
        __syncthreads();
        acc += x;
        lds[t] = acc;
        __syncthreads();
    }
    if (t < nb) boffs[t] = acc - v;
    if (t == nb - 1) rp[N] = acc;
}

__global__ void k_scan3(int* __restrict__ rp, int* __restrict__ cursor,
                        const int* __restrict__ boffs, int N) {
    int i = blockIdx.x * blockDim.x + threadIdx.x;
    if (i < N) {
        int v = rp[i] + boffs[i >> 10];
        rp[i] = v;
        cursor[i] = v;
    }
}

__global__ void k_scatter(const int* __restrict__ e, const int* __restrict__ flag,
                          int* __restrict__ cursor, int* __restrict__ col,
                          long long E, int N) {
    long long m = (long long)blockIdx.x * blockDim.x + threadIdx.x;
    long long M = E + N;
    if (m >= M) return;
    int i64 = *flag;
    int s, d;
    if (m < E) { s = eread(e, i64, m); d = eread(e, i64, E + m); }
    else { s = d = (int)(m - E); }
    int pos = atomicAdd(&cursor[d], 1);
    col[pos] = s;
}

// h = relu(x @ W1 + b1) + fused inv_norm. No LDS; W1 broadcast loads hit
// L1/L2 (same address across the 32 c-lanes). 8 rows/thread = 8 outstanding
// x-loads per k-step. block=(32,8) -> 64 rows/block.
__launch_bounds__(256) __global__
void k_gemm1(const float* __restrict__ x, const float* __restrict__ W1,
             const float* __restrict__ b1, float* __restrict__ h,
             float* __restrict__ invn, int N) {
    int c = threadIdx.x;                 // output channel 0..31
    int r0 = blockIdx.x * 64 + threadIdx.y;  // rows r0 + 8*m, m=0..7
    float bias = b1[c];
    float acc[8];
    size_t roff[8];
    bool rv[8];
#pragma unroll
    for (int m = 0; m < 8; ++m) {
        int r = r0 + 8 * m;
        rv[m] = r < N;
        roff[m] = rv[m] ? (size_t)r * 512 : 0;
        acc[m] = bias;
    }
    for (int k4 = 0; k4 < 128; ++k4) {
        float4 xv[8];
#pragma unroll
        for (int m = 0; m < 8; ++m) xv[m] = *(const float4*)(x + roff[m] + 4 * k4);
        float w0 = W1[(4 * k4 + 0) * 32 + c];
        float w1 = W1[(4 * k4 + 1) * 32 + c];
        float w2 = W1[(4 * k4 + 2) * 32 + c];
        float w3 = W1[(4 * k4 + 3) * 32 + c];
#pragma unroll
        for (int m = 0; m < 8; ++m) {
            acc[m] = fmaf(xv[m].x, w0, acc[m]);
            acc[m] = fmaf(xv[m].y, w1, acc[m]);
            acc[m] = fmaf(xv[m].z, w2, acc[m]);
            acc[m] = fmaf(xv[m].w, w3, acc[m]);
        }
    }
#pragma unroll
    for (int m = 0; m < 8; ++m) {
        int r = r0 + 8 * m;
        float hv = fmaxf(acc[m], 0.0f);
        float ss = hv * hv;
#pragma unroll
        for (int mask = 16; mask >= 1; mask >>= 1) ss += __shfl_xor(ss, mask);
        if (rv[m]) {
            h[(size_t)r * HDIM + c] = hv;
            if (c == 0) invn[r] = 1.0f / fmaxf(sqrtf(ss), 1e-12f);
        }
    }
}

// One wave per node, online softmax. Each lane gathers its edge's 128-B row
// ONCE into registers (dot product), then writes e*row to a wave-private LDS
// tile (stride LROW=36 floats, conflict-free) and reads it back transposed
// for the accumulate. Invalid lanes write zero rows -> unconditional j-loop.
__launch_bounds__(256) __global__
void k_agnn(const float* __restrict__ h_in, const float* __restrict__ inv_in,
            float* __restrict__ h_out, float* __restrict__ inv_out,
            const int* __restrict__ rp, const int* __restrict__ col, int N) {
    __shared__ float lds[4 * 64 * LROW];  // 36864 B, 4 blocks/CU
    int wave = threadIdx.x >> 6;
    int lane = threadIdx.x & 63;
    float* wl = lds + wave * (64 * LROW);
    int i = blockIdx.x * 4 + wave;
    if (i >= N) return;
    int beg = rp[i];
    int deg = rp[i + 1] - beg;
    float inv_i = inv_in[i];
    float hi[HDIM];
    {
        const float4* hp = (const float4*)(h_in + (size_t)i * HDIM);
#pragma unroll
        for (int c4 = 0; c4 < 8; ++c4) {
            float4 v = hp[c4];
            hi[4 * c4 + 0] = v.x; hi[4 * c4 + 1] = v.y;
            hi[4 * c4 + 2] = v.z; hi[4 * c4 + 3] = v.w;
        }
    }
    float m_run = -INFINITY, s_run = 0.0f;
    float4 acc = make_float4(0.f, 0.f, 0.f, 0.f);
    int g = lane & 7, joff = lane >> 3;
    for (int b = 0; b < deg; b += 64) {
        int idx = b + lane;
        bool valid = idx < deg;
        int src = valid ? col[beg + idx] : 0;
        // single gather: row -> registers, dot on the fly
        float row[HDIM];
        const float4* hs = (const float4*)(h_in + (size_t)src * HDIM);
        float dot = 0.0f;
#pragma unroll
        for (int c4 = 0; c4 < 8; ++c4) {
            float4 v = hs[c4];
            row[4 * c4 + 0] = v.x; row[4 * c4 + 1] = v.y;
            row[4 * c4 + 2] = v.z; row[4 * c4 + 3] = v.w;
            dot = fmaf(v.x, hi[4 * c4 + 0], dot);
            dot = fmaf(v.y, hi[4 * c4 + 1], dot);
            dot = fmaf(v.z, hi[4 * c4 + 2], dot);
            dot = fmaf(v.w, hi[4 * c4 + 3], dot);
        }
        float alpha = valid ? dot * inv_i * inv_in[src] : -INFINITY;
        float mc = alpha;
#pragma unroll
        for (int mask = 32; mask >= 1; mask >>= 1) mc = fmaxf(mc, __shfl_xor(mc, mask));
        float m_new = fmaxf(m_run, mc);
        float scale = __expf(m_run - m_new);  // 0 on first chunk
        float e = valid ? __expf(alpha - m_new) : 0.0f;
        float sc = e;
#pragma unroll
        for (int mask = 32; mask >= 1; mask >>= 1) sc += __shfl_xor(sc, mask);
        s_run = s_run * scale + sc;
        m_run = m_new;
        // write e*row to wave-private LDS (zero rows for invalid lanes)
        float* wp = wl + lane * LROW;
#pragma unroll
        for (int c4 = 0; c4 < 8; ++c4) {
            float4 v;
            v.x = e * row[4 * c4 + 0]; v.y = e * row[4 * c4 + 1];
            v.z = e * row[4 * c4 + 2]; v.w = e * row[4 * c4 + 3];
            *(float4*)(wp + 4 * c4) = v;
        }
        __builtin_amdgcn_wave_barrier();
        __threadfence_block();  // drain LDS writes (wave-synchronous use)
        acc.x *= scale; acc.y *= scale; acc.z *= scale; acc.w *= scale;
#pragma unroll
        for (int j = 0; j < 8; ++j) {
            float4 v = *(const float4*)(wl + (j * 8 + joff) * LROW + 4 * g);
            acc.x += v.x; acc.y += v.y; acc.z += v.z; acc.w += v.w;
        }
        __builtin_amdgcn_wave_barrier();
    }
    float invs = 1.0f / s_run;
    acc.x *= invs; acc.y *= invs; acc.z *= invs; acc.w *= invs;
#pragma unroll
    for (int mask = 8; mask <= 32; mask <<= 1) {
        acc.x += __shfl_xor(acc.x, mask);
        acc.y += __shfl_xor(acc.y, mask);
        acc.z += __shfl_xor(acc.z, mask);
        acc.w += __shfl_xor(acc.w, mask);
    }
    if (lane < 8) {
        *(float4*)(h_out + (size_t)i * HDIM + 4 * lane) = acc;
        float ss = acc.x * acc.x + acc.y * acc.y + acc.z * acc.z + acc.w * acc.w;
        ss += __shfl_xor(ss, 1);
        ss += __shfl_xor(ss, 2);
        ss += __shfl_xor(ss, 4);
        if (lane == 0) inv_out[i] = 1.0f / fmaxf(sqrtf(ss), 1e-12f);
    }
}

__launch_bounds__(256) __global__
void k_gemm2(const float* __restrict__ h, const float* __restrict__ W2,
             const float* __restrict__ b2, float* __restrict__ out, int N) {
    int wave = threadIdx.x >> 6;
    int lane = threadIdx.x & 63;
    int i = blockIdx.x * 4 + wave;
    if (i >= N) return;
    bool act = lane < 40;
    float acc = act ? b2[lane] : 0.0f;
    const float* hr = h + (size_t)i * HDIM;
#pragma unroll
    for (int k = 0; k < HDIM; ++k) {
        float hk = hr[k];
        float w = act ? W2[k * 40 + lane] : 0.0f;
        acc = fmaf(hk, w, acc);
    }
    float logit = act ? acc : -INFINITY;
    float m = logit;
#pragma unroll
    for (int mask = 32; mask >= 1; mask >>= 1) m = fmaxf(m, __shfl_xor(m, mask));
    float e = act ? __expf(logit - m) : 0.0f;
    float s = e;
#pragma unroll
    for (int mask = 32; mask >= 1; mask >>= 1) s += __shfl_xor(s, mask);
    float res = logit - m - __logf(s);
    if (act) out[(size_t)i * 40 + lane] = res;
}

extern "C" void kernel_launch(void* const* d_in, const int* in_sizes, int n_in,
                              void* d_out, int out_size, void* d_ws, size_t ws_size,
                              hipStream_t stream) {
    const float* x  = (const float*)d_in[0];
    const int*   e  = (const int*)d_in[1];
    const float* W1 = (const float*)d_in[2];
    const float* b1 = (const float*)d_in[3];
    const float* W2 = (const float*)d_in[4];
    const float* b2 = (const float*)d_in[5];
    float* out = (float*)d_out;

    const long long E = (long long)in_sizes[1] / 2;
    const int N = in_sizes[0] / 512;  // F_in = 512
    const long long M = E + N;

    char* w = (char*)d_ws;
    auto alloc = [&](size_t bytes) -> void* {
        void* p = (void*)w;
        w += (bytes + 255) & ~(size_t)255;
        return p;
    };
    int* flag    = (int*)alloc(4);
    int* deg     = (int*)alloc((size_t)N * 4);
    int* rp      = (int*)alloc(((size_t)N + 1) * 4);
    int* cursor  = (int*)alloc((size_t)N * 4);
    int* bsums   = (int*)alloc(1024);
    int* boffs   = (int*)alloc(1024);
    int* col     = (int*)alloc((size_t)M * 4);
    float* hA    = (float*)alloc((size_t)N * HDIM * 4);
    float* hB    = (float*)alloc((size_t)N * HDIM * 4);
    float* invA  = (float*)alloc((size_t)N * 4);
    float* invB  = (float*)alloc((size_t)N * 4);
    if ((size_t)(w - (char*)d_ws) > ws_size) return;

    k_flag<<<1, 64, 0, stream>>>(e, flag);
    k_zero<<<(N + 255) / 256, 256, 0, stream>>>(deg, N);
    k_count<<<(int)((M + 255) / 256), 256, 0, stream>>>(e, flag, deg, E, N);
    int nb = (N + 1023) / 1024;
    k_scan1<<<nb, 256, 0, stream>>>(deg, rp, bsums, N);
    k_scan2<<<1, 128, 0, stream>>>(bsums, boffs, rp, nb, N);
    k_scan3<<<(N + 255) / 256, 256, 0, stream>>>(rp, cursor, boffs, N);
    k_scatter<<<(int)((M + 255) / 256), 256, 0, stream>>>(e, flag, cursor, col, E, N);

    k_gemm1<<<(N + 63) / 64, dim3(32, 8), 0, stream>>>(x, W1, b1, hA, invA, N);

    float *hin = hA, *hout = hB, *iin = invA, *iout = invB;
    for (int l = 0; l < 32; ++l) {
        k_agnn<<<(N + 3) / 4, 256, 0, stream>>>(hin, iin, hout, iout, rp, col, N);
        float* t;
        t = hin; hin = hout; hout = t;
        t = iin; iin = iout; iout = t;
    }
    k_gemm2<<<(N + 3) / 4, 256, 0, stream>>>(hin, W2, b2, out, N);
}

// Round 3
// 3598.034 us; speedup vs baseline: 1.4199x; 1.3260x over previous
//
#include <hip/hip_runtime.h>
#include <math.h>

// ---------------------------------------------------------------------------
// AGNN stack: h=relu(x@W1+b1); 32x AGNNConv(beta=1); log_softmax(h@W2+b2)
// N=100000, F=512, H=32, C=40, E=3200000 (+N self loops)
// R3: k_agnn 8-lanes-per-edge (coalesced 128B row gathers, no LDS, full lane
//     utilization); k_gemm1 LDS-tiled x staging (coalesced global loads).
// ---------------------------------------------------------------------------

#define HDIM 32

static __device__ __forceinline__ int eread(const int* __restrict__ e, int i64, long long idx) {
    return i64 ? e[2 * idx] : e[idx];
}

__global__ void k_flag(const int* __restrict__ e, int* __restrict__ flag) {
    if (blockIdx.x == 0 && threadIdx.x == 0) {
        int z = 0;
        for (int k = 0; k < 64; ++k) z |= e[2 * k + 1];
        *flag = (z == 0) ? 1 : 0;
    }
}

__global__ void k_zero(int* __restrict__ deg, int N) {
    int i = blockIdx.x * blockDim.x + threadIdx.x;
    if (i < N) deg[i] = 0;
}

__global__ void k_count(const int* __restrict__ e, const int* __restrict__ flag,
                        int* __restrict__ deg, long long E, int N) {
    long long m = (long long)blockIdx.x * blockDim.x + threadIdx.x;
    long long M = E + N;
    if (m >= M) return;
    int i64 = *flag;
    int d = (m < E) ? eread(e, i64, E + m) : (int)(m - E);
    atomicAdd(&deg[d], 1);
}

__global__ void k_scan1(const int* __restrict__ deg, int* __restrict__ rp,
                        int* __restrict__ bsums, int N) {
    __shared__ int lds[256];
    int t = threadIdx.x;
    int base = blockIdx.x * 1024 + t * 4;
    int v[4];
#pragma unroll
    for (int d = 0; d < 4; ++d) v[d] = (base + d < N) ? deg[base + d] : 0;
    int tsum = v[0] + v[1] + v[2] + v[3];
    lds[t] = tsum;
    __syncthreads();
    int acc = tsum;
    for (int sh = 1; sh < 256; sh <<= 1) {
        int x = (t >= sh) ? lds[t - sh] : 0;
        __syncthreads();
        acc += x;
        lds[t] = acc;
        __syncthreads();
    }
    if (t == 255) bsums[blockIdx.x] = acc;
    int run = acc - tsum;
#pragma unroll
    for (int d = 0; d < 4; ++d) {
        if (base + d < N) rp[base + d] = run;
        run += v[d];
    }
}

__global__ void k_scan2(const int* __restrict__ bsums, int* __restrict__ boffs,
                        int* __restrict__ rp, int nb, int N) {
    __shared__ int lds[128];
    int t = threadIdx.x;
    int v = (t < nb) ? bsums[t] : 0;
    lds[t] = v;
    __syncthreads();
    int acc = v;
    for (int sh = 1; sh < 128; sh <<= 1) {
        int x = (t >= sh) ? lds[t - sh] : 0;
        __syncthreads();
        acc += x;
        lds[t] = acc;
        __syncthreads();
    }
    if (t < nb) boffs[t] = acc - v;
    if (t == nb - 1) rp[N] = acc;
}

__global__ void k_scan3(int* __restrict__ rp, int* __restrict__ cursor,
                        const int* __restrict__ boffs, int N) {
    int i = blockIdx.x * blockDim.x + threadIdx.x;
    if (i < N) {
        int v = rp[i] + boffs[i >> 10];
        rp[i] = v;
        cursor[i] = v;
    }
}

__global__ void k_scatter(const int* __restrict__ e, const int* __restrict__ flag,
                          int* __restrict__ cursor, int* __restrict__ col,
                          long long E, int N) {
    long long m = (long long)blockIdx.x * blockDim.x + threadIdx.x;
    long long M = E + N;
    if (m >= M) return;
    int i64 = *flag;
    int s, d;
    if (m < E) { s = eread(e, i64, m); d = eread(e, i64, E + m); }
    else { s = d = (int)(m - E); }
    int pos = atomicAdd(&cursor[d], 1);
    col[pos] = s;
}

// h = relu(x @ W1 + b1) + fused inv_norm. x staged in LDS with coalesced
// loads (64 rows x 64 k floats = 16 KB/chunk); compute reads are LDS
// broadcasts (2 distinct addrs/wave = free). W1 via cache (64 KB, hot).
__launch_bounds__(256) __global__
void k_gemm1(const float* __restrict__ x, const float* __restrict__ W1,
             const float* __restrict__ b1, float* __restrict__ h,
             float* __restrict__ invn, int N) {
    __shared__ float tile[64 * 64];  // 16 KiB
    int c = threadIdx.x;             // output channel 0..31
    int ty = threadIdx.y;            // 0..7
    int t = ty * 32 + c;
    int rbase = blockIdx.x * 64;
    float bias = b1[c];
    float acc[8];
#pragma unroll
    for (int m = 0; m < 8; ++m) acc[m] = bias;
    for (int kc = 0; kc < 8; ++kc) {
        if (kc) __syncthreads();
#pragma unroll
        for (int j = 0; j < 4; ++j) {
            int f = t + j * 256;          // float4 id 0..1023
            int row = f >> 4, kin = f & 15;
            int r = rbase + row;
            float4 v = make_float4(0.f, 0.f, 0.f, 0.f);
            if (r < N) v = *(const float4*)(x + (size_t)r * 512 + kc * 64 + kin * 4);
            *(float4*)(tile + row * 64 + kin * 4) = v;
        }
        __syncthreads();
#pragma unroll
        for (int k4 = 0; k4 < 16; ++k4) {
            int kk = kc * 64 + k4 * 4;
            float w0 = W1[(kk + 0) * 32 + c];
            float w1 = W1[(kk + 1) * 32 + c];
            float w2 = W1[(kk + 2) * 32 + c];
            float w3 = W1[(kk + 3) * 32 + c];
#pragma unroll
            for (int m = 0; m < 8; ++m) {
                float4 xv = *(const float4*)(tile + (ty + 8 * m) * 64 + k4 * 4);
                acc[m] = fmaf(xv.x, w0, acc[m]);
                acc[m] = fmaf(xv.y, w1, acc[m]);
                acc[m] = fmaf(xv.z, w2, acc[m]);
                acc[m] = fmaf(xv.w, w3, acc[m]);
            }
        }
    }
#pragma unroll
    for (int m = 0; m < 8; ++m) {
        int r = rbase + ty + 8 * m;
        float hv = fmaxf(acc[m], 0.0f);
        float ss = hv * hv;
#pragma unroll
        for (int mask = 16; mask >= 1; mask >>= 1) ss += __shfl_xor(ss, mask);
        if (r < N) {
            h[(size_t)r * HDIM + c] = hv;
            if (c == 0) invn[r] = 1.0f / fmaxf(sqrtf(ss), 1e-12f);
        }
    }
}

// One wave per node; 8 lanes per edge (lane = eloc*8 + c4). Each lane loads
// one float4 of its edge's row -> a wave gather touches 8 contiguous 128B
// rows (full lines) instead of 64 random 16B sectors. Dot via intra-group
// shfl (1,2,4); online softmax + accumulate via cross-group shfl (8,16,32).
// No LDS, low VGPR -> high occupancy.
__launch_bounds__(256) __global__
void k_agnn(const float* __restrict__ h_in, const float* __restrict__ inv_in,
            float* __restrict__ h_out, float* __restrict__ inv_out,
            const int* __restrict__ rp, const int* __restrict__ col, int N) {
    int wave = threadIdx.x >> 6;
    int lane = threadIdx.x & 63;
    int i = blockIdx.x * 4 + wave;
    if (i >= N) return;
    int beg = rp[i];
    int deg = rp[i + 1] - beg;
    int eloc = lane >> 3;   // edge slot within chunk, 0..7
    int c4 = lane & 7;      // column group, 0..7
    float inv_i = inv_in[i];
    float4 hi4 = *(const float4*)(h_in + (size_t)i * HDIM + 4 * c4);
    float m_run = -INFINITY, s_run = 0.0f;
    float4 acc = make_float4(0.f, 0.f, 0.f, 0.f);
    for (int b = 0; b < deg; b += 8) {
        int idx = b + eloc;
        bool valid = idx < deg;
        int src = valid ? col[beg + idx] : 0;
        float4 row = *(const float4*)(h_in + (size_t)src * HDIM + 4 * c4);
        float inv_s = inv_in[src];
        float dot = row.x * hi4.x + row.y * hi4.y + row.z * hi4.z + row.w * hi4.w;
        dot += __shfl_xor(dot, 1);
        dot += __shfl_xor(dot, 2);
        dot += __shfl_xor(dot, 4);   // full 32-elem dot, all 8 lanes of group
        float alpha = valid ? dot * inv_i * inv_s : -INFINITY;
        float mc = alpha;
        mc = fmaxf(mc, __shfl_xor(mc, 8));
        mc = fmaxf(mc, __shfl_xor(mc, 16));
        mc = fmaxf(mc, __shfl_xor(mc, 32));  // max over the 8 edges
        float m_new = fmaxf(m_run, mc);
        float scale = __expf(m_run - m_new);  // 0 on first chunk
        float e = valid ? __expf(alpha - m_new) : 0.0f;
        float sc = e;
        sc += __shfl_xor(sc, 8);
        sc += __shfl_xor(sc, 16);
        sc += __shfl_xor(sc, 32);            // sum over the 8 edges
        s_run = s_run * scale + sc;
        m_run = m_new;
        acc.x = fmaf(e, row.x, acc.x * scale);
        acc.y = fmaf(e, row.y, acc.y * scale);
        acc.z = fmaf(e, row.z, acc.z * scale);
        acc.w = fmaf(e, row.w, acc.w * scale);
    }
    // sum partial accumulators across the 8 edge groups (fixed c4)
#pragma unroll
    for (int mask = 8; mask <= 32; mask <<= 1) {
        acc.x += __shfl_xor(acc.x, mask);
        acc.y += __shfl_xor(acc.y, mask);
        acc.z += __shfl_xor(acc.z, mask);
        acc.w += __shfl_xor(acc.w, mask);
    }
    float invs = 1.0f / s_run;
    acc.x *= invs; acc.y *= invs; acc.z *= invs; acc.w *= invs;
    // inv_norm for next layer: ss per c4, reduce over c4 (masks 1,2,4)
    float ss = acc.x * acc.x + acc.y * acc.y + acc.z * acc.z + acc.w * acc.w;
    ss += __shfl_xor(ss, 1);
    ss += __shfl_xor(ss, 2);
    ss += __shfl_xor(ss, 4);
    if (lane < 8) {  // eloc==0 group: c4 = lane
        *(float4*)(h_out + (size_t)i * HDIM + 4 * lane) = acc;
        if (lane == 0) inv_out[i] = 1.0f / fmaxf(sqrtf(ss), 1e-12f);
    }
}

__launch_bounds__(256) __global__
void k_gemm2(const float* __restrict__ h, const float* __restrict__ W2,
             const float* __restrict__ b2, float* __restrict__ out, int N) {
    int wave = threadIdx.x >> 6;
    int lane = threadIdx.x & 63;
    int i = blockIdx.x * 4 + wave;
    if (i >= N) return;
    bool act = lane < 40;
    float acc = act ? b2[lane] : 0.0f;
    const float* hr = h + (size_t)i * HDIM;
#pragma unroll
    for (int k = 0; k < HDIM; ++k) {
        float hk = hr[k];
        float w = act ? W2[k * 40 + lane] : 0.0f;
        acc = fmaf(hk, w, acc);
    }
    float logit = act ? acc : -INFINITY;
    float m = logit;
#pragma unroll
    for (int mask = 32; mask >= 1; mask >>= 1) m = fmaxf(m, __shfl_xor(m, mask));
    float e = act ? __expf(logit - m) : 0.0f;
    float s = e;
#pragma unroll
    for (int mask = 32; mask >= 1; mask >>= 1) s += __shfl_xor(s, mask);
    float res = logit - m - __logf(s);
    if (act) out[(size_t)i * 40 + lane] = res;
}

extern "C" void kernel_launch(void* const* d_in, const int* in_sizes, int n_in,
                              void* d_out, int out_size, void* d_ws, size_t ws_size,
                              hipStream_t stream) {
    const float* x  = (const float*)d_in[0];
    const int*   e  = (const int*)d_in[1];
    const float* W1 = (const float*)d_in[2];
    const float* b1 = (const float*)d_in[3];
    const float* W2 = (const float*)d_in[4];
    const float* b2 = (const float*)d_in[5];
    float* out = (float*)d_out;

    const long long E = (long long)in_sizes[1] / 2;
    const int N = in_sizes[0] / 512;  // F_in = 512
    const long long M = E + N;

    char* w = (char*)d_ws;
    auto alloc = [&](size_t bytes) -> void* {
        void* p = (void*)w;
        w += (bytes + 255) & ~(size_t)255;
        return p;
    };
    int* flag    = (int*)alloc(4);
    int* deg     = (int*)alloc((size_t)N * 4);
    int* rp      = (int*)alloc(((size_t)N + 1) * 4);
    int* cursor  = (int*)alloc((size_t)N * 4);
    int* bsums   = (int*)alloc(1024);
    int* boffs   = (int*)alloc(1024);
    int* col     = (int*)alloc((size_t)M * 4);
    float* hA    = (float*)alloc((size_t)N * HDIM * 4);
    float* hB    = (float*)alloc((size_t)N * HDIM * 4);
    float* invA  = (float*)alloc((size_t)N * 4);
    float* invB  = (float*)alloc((size_t)N * 4);
    if ((size_t)(w - (char*)d_ws) > ws_size) return;

    k_flag<<<1, 64, 0, stream>>>(e, flag);
    k_zero<<<(N + 255) / 256, 256, 0, stream>>>(deg, N);
    k_count<<<(int)((M + 255) / 256), 256, 0, stream>>>(e, flag, deg, E, N);
    int nb = (N + 1023) / 1024;
    k_scan1<<<nb, 256, 0, stream>>>(deg, rp, bsums, N);
    k_scan2<<<1, 128, 0, stream>>>(bsums, boffs, rp, nb, N);
    k_scan3<<<(N + 255) / 256, 256, 0, stream>>>(rp, cursor, boffs, N);
    k_scatter<<<(int)((M + 255) / 256), 256, 0, stream>>>(e, flag, cursor, col, E, N);

    k_gemm1<<<(N + 63) / 64, dim3(32, 8), 0, stream>>>(x, W1, b1, hA, invA, N);

    float *hin = hA, *hout = hB, *iin = invA, *iout = invB;
    for (int l = 0; l < 32; ++l) {
        k_agnn<<<(N + 3) / 4, 256, 0, stream>>>(hin, iin, hout, iout, rp, col, N);
        float* t;
        t = hin; hin = hout; hout = t;
        t = iin; iin = iout; iout = t;
    }
    k_gemm2<<<(N + 3) / 4, 256, 0, stream>>>(hin, W2, b2, out, N);
}

// Round 4
// 2866.460 us; speedup vs baseline: 1.7822x; 1.2552x over previous
//
#include <hip/hip_runtime.h>
#include <math.h>

// ---------------------------------------------------------------------------
// AGNN stack: h=relu(x@W1+b1); 32x AGNNConv(beta=1); log_softmax(h@W2+b2)
// N=100000, F=512, H=32, C=40, E=3200000 (+N self loops)
// R4: CSR build via 2-level radix partition (LDS histograms, ~100K global
//     atomics instead of 6.6M); k_agnn software-pipelined gathers + batched
//     col loads.
// ---------------------------------------------------------------------------

#define HDIM 32
#define NBMAX 1024   // bucket table size (needs N <= 128*1024)
#define BSH 7        // 128 dsts per bucket
#define CHUNK 32768  // edges per partition block

static __device__ __forceinline__ int eread(const int* __restrict__ e, int i64, long long idx) {
    return i64 ? e[2 * idx] : e[idx];
}

__global__ void k_flag(const int* __restrict__ e, int* __restrict__ flag) {
    if (blockIdx.x == 0 && threadIdx.x == 0) {
        int z = 0;
        for (int k = 0; k < 64; ++k) z |= e[2 * k + 1];
        *flag = (z == 0) ? 1 : 0;
    }
}

__global__ void k_zero(int* __restrict__ p, int n) {
    int i = blockIdx.x * blockDim.x + threadIdx.x;
    if (i < n) p[i] = 0;
}

// Pass 1: per-block LDS histogram over dst buckets + global reserve.
__launch_bounds__(256) __global__
void k_hist(const int* __restrict__ e, const int* __restrict__ flag,
            int* __restrict__ gc, int* __restrict__ blockOffs,
            long long E, long long M) {
    __shared__ int bh[NBMAX];
    for (int t = threadIdx.x; t < NBMAX; t += 256) bh[t] = 0;
    __syncthreads();
    int i64 = *flag;
    long long base = (long long)blockIdx.x * CHUNK;
    long long end = base + CHUNK < M ? base + CHUNK : M;
    for (long long m = base + threadIdx.x; m < end; m += 256) {
        int d = (m < E) ? eread(e, i64, E + m) : (int)(m - E);
        atomicAdd(&bh[d >> BSH], 1);
    }
    __syncthreads();
    for (int t = threadIdx.x; t < NBMAX; t += 256) {
        int c = bh[t];
        int off = 0;
        if (c) off = atomicAdd(&gc[t], c);
        blockOffs[(size_t)blockIdx.x * NBMAX + t] = off;
    }
}

// Scan the 1024 bucket counts (single block). bbase[NBMAX]=total, rp[N]=total.
__launch_bounds__(256) __global__
void k_bscan(const int* __restrict__ gc, int* __restrict__ bbase,
             int* __restrict__ rp, int N) {
    __shared__ int lds[256];
    int t = threadIdx.x;
    int v[4];
#pragma unroll
    for (int d = 0; d < 4; ++d) v[d] = gc[t * 4 + d];
    int tsum = v[0] + v[1] + v[2] + v[3];
    lds[t] = tsum;
    __syncthreads();
    int acc = tsum;
    for (int sh = 1; sh < 256; sh <<= 1) {
        int x = (t >= sh) ? lds[t - sh] : 0;
        __syncthreads();
        acc += x;
        lds[t] = acc;
        __syncthreads();
    }
    if (t == 255) { rp[N] = acc; bbase[NBMAX] = acc; }
    int run = acc - tsum;
#pragma unroll
    for (int d = 0; d < 4; ++d) { bbase[t * 4 + d] = run; run += v[d]; }
}

// Pass 2: partition edges into bucket regions (same chunking as k_hist).
__launch_bounds__(256) __global__
void k_part(const int* __restrict__ e, const int* __restrict__ flag,
            const int* __restrict__ bbase, const int* __restrict__ blockOffs,
            int2* __restrict__ pair, long long E, long long M) {
    __shared__ int cur[NBMAX];
    for (int t = threadIdx.x; t < NBMAX; t += 256)
        cur[t] = bbase[t] + blockOffs[(size_t)blockIdx.x * NBMAX + t];
    __syncthreads();
    int i64 = *flag;
    long long base = (long long)blockIdx.x * CHUNK;
    long long end = base + CHUNK < M ? base + CHUNK : M;
    for (long long m = base + threadIdx.x; m < end; m += 256) {
        int s, d;
        if (m < E) { s = eread(e, i64, m); d = eread(e, i64, E + m); }
        else { s = d = (int)(m - E); }
        int pos = atomicAdd(&cur[d >> BSH], 1);
        pair[pos] = make_int2(s, d);
    }
}

// Pass 3: one block per bucket -> fine CSR (rp + col), all LDS atomics.
__launch_bounds__(256) __global__
void k_fine(const int2* __restrict__ pair, const int* __restrict__ bbase,
            int* __restrict__ rp, int* __restrict__ col, int N) {
    __shared__ int cnt[128];
    __shared__ int sc[128];
    int b = blockIdx.x;
    int beg = bbase[b];
    int end = bbase[b + 1];
    int t = threadIdx.x;
    if (t < 128) cnt[t] = 0;
    __syncthreads();
    for (int k = beg + t; k < end; k += 256)
        atomicAdd(&cnt[pair[k].y & 127], 1);
    __syncthreads();
    if (t < 128) sc[t] = cnt[t];
    __syncthreads();
    for (int sh = 1; sh < 128; sh <<= 1) {
        int x = 0;
        if (t < 128 && t >= sh) x = sc[t - sh];
        __syncthreads();
        if (t < 128) sc[t] += x;
        __syncthreads();
    }
    if (t < 128) {
        int basepos = beg + sc[t] - cnt[t];  // exclusive
        int d = (b << BSH) + t;
        if (d < N) rp[d] = basepos;
        cnt[t] = basepos;  // reuse as absolute cursor
    }
    __syncthreads();
    for (int k = beg + t; k < end; k += 256) {
        int2 p = pair[k];
        int pos = atomicAdd(&cnt[p.y & 127], 1);
        col[pos] = p.x;
    }
}

// h = relu(x @ W1 + b1) + fused inv_norm. LDS-tiled x staging.
__launch_bounds__(256) __global__
void k_gemm1(const float* __restrict__ x, const float* __restrict__ W1,
             const float* __restrict__ b1, float* __restrict__ h,
             float* __restrict__ invn, int N) {
    __shared__ float tile[64 * 64];  // 16 KiB
    int c = threadIdx.x;
    int ty = threadIdx.y;
    int t = ty * 32 + c;
    int rbase = blockIdx.x * 64;
    float bias = b1[c];
    float acc[8];
#pragma unroll
    for (int m = 0; m < 8; ++m) acc[m] = bias;
    for (int kc = 0; kc < 8; ++kc) {
        if (kc) __syncthreads();
#pragma unroll
        for (int j = 0; j < 4; ++j) {
            int f = t + j * 256;
            int row = f >> 4, kin = f & 15;
            int r = rbase + row;
            float4 v = make_float4(0.f, 0.f, 0.f, 0.f);
            if (r < N) v = *(const float4*)(x + (size_t)r * 512 + kc * 64 + kin * 4);
            *(float4*)(tile + row * 64 + kin * 4) = v;
        }
        __syncthreads();
#pragma unroll
        for (int k4 = 0; k4 < 16; ++k4) {
            int kk = kc * 64 + k4 * 4;
            float w0 = W1[(kk + 0) * 32 + c];
            float w1 = W1[(kk + 1) * 32 + c];
            float w2 = W1[(kk + 2) * 32 + c];
            float w3 = W1[(kk + 3) * 32 + c];
#pragma unroll
            for (int m = 0; m < 8; ++m) {
                float4 xv = *(const float4*)(tile + (ty + 8 * m) * 64 + k4 * 4);
                acc[m] = fmaf(xv.x, w0, acc[m]);
                acc[m] = fmaf(xv.y, w1, acc[m]);
                acc[m] = fmaf(xv.z, w2, acc[m]);
                acc[m] = fmaf(xv.w, w3, acc[m]);
            }
        }
    }
#pragma unroll
    for (int m = 0; m < 8; ++m) {
        int r = rbase + ty + 8 * m;
        float hv = fmaxf(acc[m], 0.0f);
        float ss = hv * hv;
#pragma unroll
        for (int mask = 16; mask >= 1; mask >>= 1) ss += __shfl_xor(ss, mask);
        if (r < N) {
            h[(size_t)r * HDIM + c] = hv;
            if (c == 0) invn[r] = 1.0f / fmaxf(sqrtf(ss), 1e-12f);
        }
    }
}

// One wave per node; 8 lanes per edge. Software-pipelined: next chunk's
// src/row/inv loads issue before current chunk's shfl/exp chain. col is
// batch-loaded 64 entries at a time and broadcast by shfl.
__launch_bounds__(256) __global__
void k_agnn(const float* __restrict__ h_in, const float* __restrict__ inv_in,
            float* __restrict__ h_out, float* __restrict__ inv_out,
            const int* __restrict__ rp, const int* __restrict__ col, int N) {
    int wave = threadIdx.x >> 6;
    int lane = threadIdx.x & 63;
    int i = blockIdx.x * 4 + wave;
    if (i >= N) return;
    int beg = rp[i];
    int deg = rp[i + 1] - beg;
    int eloc = lane >> 3;   // edge slot 0..7
    int c4 = lane & 7;      // column group 0..7
    float inv_i = inv_in[i];
    float4 hi4 = *(const float4*)(h_in + (size_t)i * HDIM + 4 * c4);
    float m_run = -INFINITY, s_run = 0.0f;
    float4 acc = make_float4(0.f, 0.f, 0.f, 0.f);
    int nchunk = (deg + 7) >> 3;
    // col batch covering chunks 0..7
    int cv = (lane < deg) ? col[beg + lane] : 0;
    // prefetch chunk 0
    int src = __shfl(cv, eloc);
    bool valid = eloc < deg;
    src = valid ? src : 0;
    float4 row = *(const float4*)(h_in + (size_t)src * HDIM + 4 * c4);
    float inv_s = inv_in[src];
    for (int ck = 0; ck < nchunk; ++ck) {
        float4 rcur = row;
        float icur = inv_s;
        bool vcur = valid;
        int nc = ck + 1;
        if (nc < nchunk) {  // wave-uniform
            if ((nc & 7) == 0) {
                int idx64 = nc * 8 + lane;
                cv = (idx64 < deg) ? col[beg + idx64] : 0;
            }
            int idx = nc * 8 + eloc;
            valid = idx < deg;
            src = __shfl(cv, ((nc & 7) << 3) | eloc);
            src = valid ? src : 0;
            row = *(const float4*)(h_in + (size_t)src * HDIM + 4 * c4);
            inv_s = inv_in[src];
        }
        // compute current chunk
        float dot = rcur.x * hi4.x + rcur.y * hi4.y + rcur.z * hi4.z + rcur.w * hi4.w;
        dot += __shfl_xor(dot, 1);
        dot += __shfl_xor(dot, 2);
        dot += __shfl_xor(dot, 4);
        float alpha = vcur ? dot * inv_i * icur : -INFINITY;
        float mc = alpha;
        mc = fmaxf(mc, __shfl_xor(mc, 8));
        mc = fmaxf(mc, __shfl_xor(mc, 16));
        mc = fmaxf(mc, __shfl_xor(mc, 32));
        float m_new = fmaxf(m_run, mc);
        float scale = __expf(m_run - m_new);
        float e = vcur ? __expf(alpha - m_new) : 0.0f;
        float sc2 = e;
        sc2 += __shfl_xor(sc2, 8);
        sc2 += __shfl_xor(sc2, 16);
        sc2 += __shfl_xor(sc2, 32);
        s_run = s_run * scale + sc2;
        m_run = m_new;
        acc.x = fmaf(e, rcur.x, acc.x * scale);
        acc.y = fmaf(e, rcur.y, acc.y * scale);
        acc.z = fmaf(e, rcur.z, acc.z * scale);
        acc.w = fmaf(e, rcur.w, acc.w * scale);
    }
#pragma unroll
    for (int mask = 8; mask <= 32; mask <<= 1) {
        acc.x += __shfl_xor(acc.x, mask);
        acc.y += __shfl_xor(acc.y, mask);
        acc.z += __shfl_xor(acc.z, mask);
        acc.w += __shfl_xor(acc.w, mask);
    }
    float invs = 1.0f / s_run;
    acc.x *= invs; acc.y *= invs; acc.z *= invs; acc.w *= invs;
    float ss = acc.x * acc.x + acc.y * acc.y + acc.z * acc.z + acc.w * acc.w;
    ss += __shfl_xor(ss, 1);
    ss += __shfl_xor(ss, 2);
    ss += __shfl_xor(ss, 4);
    if (lane < 8) {
        *(float4*)(h_out + (size_t)i * HDIM + 4 * lane) = acc;
        if (lane == 0) inv_out[i] = 1.0f / fmaxf(sqrtf(ss), 1e-12f);
    }
}

__launch_bounds__(256) __global__
void k_gemm2(const float* __restrict__ h, const float* __restrict__ W2,
             const float* __restrict__ b2, float* __restrict__ out, int N) {
    int wave = threadIdx.x >> 6;
    int lane = threadIdx.x & 63;
    int i = blockIdx.x * 4 + wave;
    if (i >= N) return;
    bool act = lane < 40;
    float acc = act ? b2[lane] : 0.0f;
    const float* hr = h + (size_t)i * HDIM;
#pragma unroll
    for (int k = 0; k < HDIM; ++k) {
        float hk = hr[k];
        float w = act ? W2[k * 40 + lane] : 0.0f;
        acc = fmaf(hk, w, acc);
    }
    float logit = act ? acc : -INFINITY;
    float m = logit;
#pragma unroll
    for (int mask = 32; mask >= 1; mask >>= 1) m = fmaxf(m, __shfl_xor(m, mask));
    float e = act ? __expf(logit - m) : 0.0f;
    float s = e;
#pragma unroll
    for (int mask = 32; mask >= 1; mask >>= 1) s += __shfl_xor(s, mask);
    float res = logit - m - __logf(s);
    if (act) out[(size_t)i * 40 + lane] = res;
}

extern "C" void kernel_launch(void* const* d_in, const int* in_sizes, int n_in,
                              void* d_out, int out_size, void* d_ws, size_t ws_size,
                              hipStream_t stream) {
    const float* x  = (const float*)d_in[0];
    const int*   e  = (const int*)d_in[1];
    const float* W1 = (const float*)d_in[2];
    const float* b1 = (const float*)d_in[3];
    const float* W2 = (const float*)d_in[4];
    const float* b2 = (const float*)d_in[5];
    float* out = (float*)d_out;

    const long long E = (long long)in_sizes[1] / 2;
    const int N = in_sizes[0] / 512;  // F_in = 512
    const long long M = E + N;
    const int nblk = (int)((M + CHUNK - 1) / CHUNK);

    char* w = (char*)d_ws;
    auto alloc = [&](size_t bytes) -> void* {
        void* p = (void*)w;
        w += (bytes + 255) & ~(size_t)255;
        return p;
    };
    int*  flag      = (int*)alloc(4);
    int*  gc        = (int*)alloc(NBMAX * 4);
    int*  bbase     = (int*)alloc((NBMAX + 1) * 4);
    int*  blockOffs = (int*)alloc((size_t)nblk * NBMAX * 4);
    int2* pair      = (int2*)alloc((size_t)M * 8);
    int*  rp        = (int*)alloc(((size_t)N + 1) * 4);
    int*  col       = (int*)alloc((size_t)M * 4);
    float* hA   = (float*)alloc((size_t)N * HDIM * 4);
    float* hB   = (float*)alloc((size_t)N * HDIM * 4);
    float* invA = (float*)alloc((size_t)N * 4);
    float* invB = (float*)alloc((size_t)N * 4);
    if ((size_t)(w - (char*)d_ws) > ws_size) return;

    k_flag<<<1, 64, 0, stream>>>(e, flag);
    k_zero<<<(NBMAX + 255) / 256, 256, 0, stream>>>(gc, NBMAX);
    k_hist<<<nblk, 256, 0, stream>>>(e, flag, gc, blockOffs, E, M);
    k_bscan<<<1, 256, 0, stream>>>(gc, bbase, rp, N);
    k_part<<<nblk, 256, 0, stream>>>(e, flag, bbase, blockOffs, pair, E, M);
    k_fine<<<NBMAX, 256, 0, stream>>>(pair, bbase, rp, col, N);

    k_gemm1<<<(N + 63) / 64, dim3(32, 8), 0, stream>>>(x, W1, b1, hA, invA, N);

    float *hin = hA, *hout = hB, *iin = invA, *iout = invB;
    for (int l = 0; l < 32; ++l) {
        k_agnn<<<(N + 3) / 4, 256, 0, stream>>>(hin, iin, hout, iout, rp, col, N);
        float* t;
        t = hin; hin = hout; hout = t;
        t = iin; iin = iout; iout = t;
    }
    k_gemm2<<<(N + 3) / 4, 256, 0, stream>>>(hin, W2, b2, out, N);
}

// Round 5
// 2830.385 us; speedup vs baseline: 1.8050x; 1.0127x over previous
//
#include <hip/hip_runtime.h>
#include <math.h>

// ---------------------------------------------------------------------------
// AGNN stack: h=relu(x@W1+b1); 32x AGNNConv(beta=1); log_softmax(h@W2+b2)
// N=100000, F=512, H=32, C=40, E=3200000 (+N self loops)
// R5: h stored fp16 (64B rows -> half gather traffic, better L2 residency),
//     dot via v_dot2_f32_f16, fp32 softmax/accum/norms;
//     k_gemm1 register-blocked c (4 c/thread) -> 4x less LDS amplification,
//     tile stride padded to 68 to kill the new 8-way bank conflict.
// ---------------------------------------------------------------------------

#define HDIM 32
#define NBMAX 1024   // bucket table size (needs N <= 128*1024)
#define BSH 7        // 128 dsts per bucket
#define CHUNK 32768  // edges per partition block
#define TP 68        // padded gemm1 tile stride (floats)

typedef _Float16 f16;
typedef _Float16 v2h __attribute__((ext_vector_type(2)));

struct __attribute__((aligned(16))) H8 { v2h p[4]; };  // one fp16 half-row (8 elems)
struct __attribute__((aligned(8)))  H4 { v2h p[2]; };  // 4 fp16 elems

#if defined(__has_builtin)
#if __has_builtin(__builtin_amdgcn_fdot2)
#define FDOT2(a, b, c) __builtin_amdgcn_fdot2((a), (b), (c), false)
#endif
#endif
#ifndef FDOT2
#define FDOT2(a, b, c) fmaf((float)(a)[1], (float)(b)[1], fmaf((float)(a)[0], (float)(b)[0], (c)))
#endif

static __device__ __forceinline__ int eread(const int* __restrict__ e, int i64, long long idx) {
    return i64 ? e[2 * idx] : e[idx];
}

__global__ void k_flag(const int* __restrict__ e, int* __restrict__ flag) {
    if (blockIdx.x == 0 && threadIdx.x == 0) {
        int z = 0;
        for (int k = 0; k < 64; ++k) z |= e[2 * k + 1];
        *flag = (z == 0) ? 1 : 0;
    }
}

__global__ void k_zero(int* __restrict__ p, int n) {
    int i = blockIdx.x * blockDim.x + threadIdx.x;
    if (i < n) p[i] = 0;
}

// Pass 1: per-block LDS histogram over dst buckets + global reserve.
__launch_bounds__(256) __global__
void k_hist(const int* __restrict__ e, const int* __restrict__ flag,
            int* __restrict__ gc, int* __restrict__ blockOffs,
            long long E, long long M) {
    __shared__ int bh[NBMAX];
    for (int t = threadIdx.x; t < NBMAX; t += 256) bh[t] = 0;
    __syncthreads();
    int i64 = *flag;
    long long base = (long long)blockIdx.x * CHUNK;
    long long end = base + CHUNK < M ? base + CHUNK : M;
    for (long long m = base + threadIdx.x; m < end; m += 256) {
        int d = (m < E) ? eread(e, i64, E + m) : (int)(m - E);
        atomicAdd(&bh[d >> BSH], 1);
    }
    __syncthreads();
    for (int t = threadIdx.x; t < NBMAX; t += 256) {
        int c = bh[t];
        int off = 0;
        if (c) off = atomicAdd(&gc[t], c);
        blockOffs[(size_t)blockIdx.x * NBMAX + t] = off;
    }
}

__launch_bounds__(256) __global__
void k_bscan(const int* __restrict__ gc, int* __restrict__ bbase,
             int* __restrict__ rp, int N) {
    __shared__ int lds[256];
    int t = threadIdx.x;
    int v[4];
#pragma unroll
    for (int d = 0; d < 4; ++d) v[d] = gc[t * 4 + d];
    int tsum = v[0] + v[1] + v[2] + v[3];
    lds[t] = tsum;
    __syncthreads();
    int acc = tsum;
    for (int sh = 1; sh < 256; sh <<= 1) {
        int x = (t >= sh) ? lds[t - sh] : 0;
        __syncthreads();
        acc += x;
        lds[t] = acc;
        __syncthreads();
    }
    if (t == 255) { rp[N] = acc; bbase[NBMAX] = acc; }
    int run = acc - tsum;
#pragma unroll
    for (int d = 0; d < 4; ++d) { bbase[t * 4 + d] = run; run += v[d]; }
}

// Pass 2: partition edges into bucket regions.
__launch_bounds__(256) __global__
void k_part(const int* __restrict__ e, const int* __restrict__ flag,
            const int* __restrict__ bbase, const int* __restrict__ blockOffs,
            int2* __restrict__ pair, long long E, long long M) {
    __shared__ int cur[NBMAX];
    for (int t = threadIdx.x; t < NBMAX; t += 256)
        cur[t] = bbase[t] + blockOffs[(size_t)blockIdx.x * NBMAX + t];
    __syncthreads();
    int i64 = *flag;
    long long base = (long long)blockIdx.x * CHUNK;
    long long end = base + CHUNK < M ? base + CHUNK : M;
    for (long long m = base + threadIdx.x; m < end; m += 256) {
        int s, d;
        if (m < E) { s = eread(e, i64, m); d = eread(e, i64, E + m); }
        else { s = d = (int)(m - E); }
        int pos = atomicAdd(&cur[d >> BSH], 1);
        pair[pos] = make_int2(s, d);
    }
}

// Pass 3: one block per bucket -> fine CSR (rp + col), all LDS atomics.
__launch_bounds__(256) __global__
void k_fine(const int2* __restrict__ pair, const int* __restrict__ bbase,
            int* __restrict__ rp, int* __restrict__ col, int N) {
    __shared__ int cnt[128];
    __shared__ int sc[128];
    int b = blockIdx.x;
    int beg = bbase[b];
    int end = bbase[b + 1];
    int t = threadIdx.x;
    if (t < 128) cnt[t] = 0;
    __syncthreads();
    for (int k = beg + t; k < end; k += 256)
        atomicAdd(&cnt[pair[k].y & 127], 1);
    __syncthreads();
    if (t < 128) sc[t] = cnt[t];
    __syncthreads();
    for (int sh = 1; sh < 128; sh <<= 1) {
        int x = 0;
        if (t < 128 && t >= sh) x = sc[t - sh];
        __syncthreads();
        if (t < 128) sc[t] += x;
        __syncthreads();
    }
    if (t < 128) {
        int basepos = beg + sc[t] - cnt[t];
        int d = (b << BSH) + t;
        if (d < N) rp[d] = basepos;
        cnt[t] = basepos;
    }
    __syncthreads();
    for (int k = beg + t; k < end; k += 256) {
        int2 p = pair[k];
        int pos = atomicAdd(&cnt[p.y & 127], 1);
        col[pos] = p.x;
    }
}

// h = relu(x @ W1 + b1) + fused inv_norm, fp16 h output.
// Thread (cg=tid&7, ty=tid>>3) computes rows {ty, ty+32} x cols {4cg..4cg+3}.
// LDS amplification 8x (was 32x); tile stride 68 -> conflict-free reads.
__launch_bounds__(256) __global__
void k_gemm1(const float* __restrict__ x, const float* __restrict__ W1,
             const float* __restrict__ b1, f16* __restrict__ h,
             float* __restrict__ invn, int N) {
    __shared__ float tile[64 * TP];  // 17408 B
    int tid = threadIdx.x;
    int cg = tid & 7;   // c = 4*cg .. 4*cg+3
    int ty = tid >> 3;  // 0..31
    int rbase = blockIdx.x * 64;
    float4 bias = *(const float4*)(b1 + 4 * cg);
    float acc[2][4];
#pragma unroll
    for (int m = 0; m < 2; ++m) {
        acc[m][0] = bias.x; acc[m][1] = bias.y;
        acc[m][2] = bias.z; acc[m][3] = bias.w;
    }
    for (int kc = 0; kc < 8; ++kc) {
        if (kc) __syncthreads();
#pragma unroll
        for (int j = 0; j < 4; ++j) {
            int f = tid + j * 256;  // float4 slot 0..1023 = 64 rows x 16
            int row = f >> 4, kin = f & 15;
            int r = rbase + row;
            float4 v = make_float4(0.f, 0.f, 0.f, 0.f);
            if (r < N) v = *(const float4*)(x + (size_t)r * 512 + kc * 64 + kin * 4);
            *(float4*)(tile + row * TP + kin * 4) = v;
        }
        __syncthreads();
#pragma unroll
        for (int k4 = 0; k4 < 16; ++k4) {
            int kk = kc * 64 + k4 * 4;
            float4 w0 = *(const float4*)(W1 + (size_t)(kk + 0) * 32 + 4 * cg);
            float4 w1 = *(const float4*)(W1 + (size_t)(kk + 1) * 32 + 4 * cg);
            float4 w2 = *(const float4*)(W1 + (size_t)(kk + 2) * 32 + 4 * cg);
            float4 w3 = *(const float4*)(W1 + (size_t)(kk + 3) * 32 + 4 * cg);
#pragma unroll
            for (int m = 0; m < 2; ++m) {
                float4 xv = *(const float4*)(tile + (ty + 32 * m) * TP + k4 * 4);
                acc[m][0] = fmaf(xv.x, w0.x, acc[m][0]);
                acc[m][1] = fmaf(xv.x, w0.y, acc[m][1]);
                acc[m][2] = fmaf(xv.x, w0.z, acc[m][2]);
                acc[m][3] = fmaf(xv.x, w0.w, acc[m][3]);
                acc[m][0] = fmaf(xv.y, w1.x, acc[m][0]);
                acc[m][1] = fmaf(xv.y, w1.y, acc[m][1]);
                acc[m][2] = fmaf(xv.y, w1.z, acc[m][2]);
                acc[m][3] = fmaf(xv.y, w1.w, acc[m][3]);
                acc[m][0] = fmaf(xv.z, w2.x, acc[m][0]);
                acc[m][1] = fmaf(xv.z, w2.y, acc[m][1]);
                acc[m][2] = fmaf(xv.z, w2.z, acc[m][2]);
                acc[m][3] = fmaf(xv.z, w2.w, acc[m][3]);
                acc[m][0] = fmaf(xv.w, w3.x, acc[m][0]);
                acc[m][1] = fmaf(xv.w, w3.y, acc[m][1]);
                acc[m][2] = fmaf(xv.w, w3.z, acc[m][2]);
                acc[m][3] = fmaf(xv.w, w3.w, acc[m][3]);
            }
        }
    }
#pragma unroll
    for (int m = 0; m < 2; ++m) {
        int r = rbase + ty + 32 * m;
        float hv[4];
        float ss = 0.0f;
#pragma unroll
        for (int j = 0; j < 4; ++j) {
            hv[j] = fmaxf(acc[m][j], 0.0f);
            ss = fmaf(hv[j], hv[j], ss);
        }
        ss += __shfl_xor(ss, 1);
        ss += __shfl_xor(ss, 2);
        ss += __shfl_xor(ss, 4);  // sum over cg
        if (r < N) {
            H4 o;
            o.p[0][0] = (f16)hv[0]; o.p[0][1] = (f16)hv[1];
            o.p[1][0] = (f16)hv[2]; o.p[1][1] = (f16)hv[3];
            *(H4*)(h + (size_t)r * HDIM + 4 * cg) = o;
            if (cg == 0) invn[r] = 1.0f / fmaxf(sqrtf(ss), 1e-12f);
        }
    }
}

// One wave per node; 4 lanes per edge, 16 edges per chunk (fp16 rows = 64B).
// eloc = lane>>2 (edge slot), c8 = lane&3 (8 h-elements each). Dot via
// v_dot2_f32_f16, fp32 softmax/accum. Software-pipelined next-chunk loads.
__launch_bounds__(256) __global__
void k_agnn(const f16* __restrict__ h_in, const float* __restrict__ inv_in,
            f16* __restrict__ h_out, float* __restrict__ inv_out,
            const int* __restrict__ rp, const int* __restrict__ col, int N) {
    int wave = threadIdx.x >> 6;
    int lane = threadIdx.x & 63;
    int i = blockIdx.x * 4 + wave;
    if (i >= N) return;
    int beg = rp[i];
    int deg = rp[i + 1] - beg;
    int eloc = lane >> 2;  // 0..15
    int c8 = lane & 3;     // element group (8 halfs)
    float inv_i = inv_in[i];
    H8 hi = *(const H8*)(h_in + (size_t)i * HDIM + 8 * c8);
    float m_run = -INFINITY, s_run = 0.0f;
    float acc[8] = {0.f, 0.f, 0.f, 0.f, 0.f, 0.f, 0.f, 0.f};
    int nchunk = (deg + 15) >> 4;
    // col batch covers chunks 0..3
    int cv = (lane < deg) ? col[beg + lane] : 0;
    // prefetch chunk 0
    int src = __shfl(cv, eloc);
    bool valid = eloc < deg;
    src = valid ? src : 0;
    H8 row = *(const H8*)(h_in + (size_t)src * HDIM + 8 * c8);
    float inv_s = inv_in[src];
    for (int ck = 0; ck < nchunk; ++ck) {
        H8 rcur = row;
        float icur = inv_s;
        bool vcur = valid;
        int nc = ck + 1;
        if (nc < nchunk) {  // wave-uniform branch
            if ((nc & 3) == 0) {
                int idx64 = nc * 16 + lane;
                cv = (idx64 < deg) ? col[beg + idx64] : 0;
            }
            int idx = nc * 16 + eloc;
            valid = idx < deg;
            src = __shfl(cv, ((nc & 3) << 4) | eloc);
            src = valid ? src : 0;
            row = *(const H8*)(h_in + (size_t)src * HDIM + 8 * c8);
            inv_s = inv_in[src];
        }
        // dot over this lane's 8 elements, fp32 accumulate
        float dot = 0.0f;
#pragma unroll
        for (int j = 0; j < 4; ++j) dot = FDOT2(rcur.p[j], hi.p[j], dot);
        dot += __shfl_xor(dot, 1);
        dot += __shfl_xor(dot, 2);  // full 32-elem dot within 4-lane group
        float alpha = vcur ? dot * inv_i * icur : -INFINITY;
        float mc = alpha;
        mc = fmaxf(mc, __shfl_xor(mc, 4));
        mc = fmaxf(mc, __shfl_xor(mc, 8));
        mc = fmaxf(mc, __shfl_xor(mc, 16));
        mc = fmaxf(mc, __shfl_xor(mc, 32));
        float m_new = fmaxf(m_run, mc);
        float scale = __expf(m_run - m_new);
        float e = vcur ? __expf(alpha - m_new) : 0.0f;
        float sc = e;
        sc += __shfl_xor(sc, 4);
        sc += __shfl_xor(sc, 8);
        sc += __shfl_xor(sc, 16);
        sc += __shfl_xor(sc, 32);
        s_run = s_run * scale + sc;
        m_run = m_new;
#pragma unroll
        for (int j = 0; j < 4; ++j) {
            acc[2 * j + 0] = fmaf(acc[2 * j + 0], scale, e * (float)rcur.p[j][0]);
            acc[2 * j + 1] = fmaf(acc[2 * j + 1], scale, e * (float)rcur.p[j][1]);
        }
    }
    // sum partial accumulators across the 16 edge groups (fixed c8)
#pragma unroll
    for (int mask = 4; mask <= 32; mask <<= 1) {
#pragma unroll
        for (int j = 0; j < 8; ++j) acc[j] += __shfl_xor(acc[j], mask);
    }
    float invs = 1.0f / s_run;
    float ss = 0.0f;
#pragma unroll
    for (int j = 0; j < 8; ++j) {
        acc[j] *= invs;
        ss = fmaf(acc[j], acc[j], ss);
    }
    ss += __shfl_xor(ss, 1);
    ss += __shfl_xor(ss, 2);  // sum over the 4 c8 groups
    if (lane < 4) {  // eloc==0: c8 = lane
        H8 o;
#pragma unroll
        for (int j = 0; j < 4; ++j) {
            o.p[j][0] = (f16)acc[2 * j + 0];
            o.p[j][1] = (f16)acc[2 * j + 1];
        }
        *(H8*)(h_out + (size_t)i * HDIM + 8 * lane) = o;
        if (lane == 0) inv_out[i] = 1.0f / fmaxf(sqrtf(ss), 1e-12f);
    }
}

__launch_bounds__(256) __global__
void k_gemm2(const f16* __restrict__ h, const float* __restrict__ W2,
             const float* __restrict__ b2, float* __restrict__ out, int N) {
    int wave = threadIdx.x >> 6;
    int lane = threadIdx.x & 63;
    int i = blockIdx.x * 4 + wave;
    if (i >= N) return;
    bool act = lane < 40;
    float acc = act ? b2[lane] : 0.0f;
    const f16* hr = h + (size_t)i * HDIM;
#pragma unroll
    for (int k = 0; k < HDIM; ++k) {
        float hk = (float)hr[k];
        float w = act ? W2[k * 40 + lane] : 0.0f;
        acc = fmaf(hk, w, acc);
    }
    float logit = act ? acc : -INFINITY;
    float m = logit;
#pragma unroll
    for (int mask = 32; mask >= 1; mask >>= 1) m = fmaxf(m, __shfl_xor(m, mask));
    float e = act ? __expf(logit - m) : 0.0f;
    float s = e;
#pragma unroll
    for (int mask = 32; mask >= 1; mask >>= 1) s += __shfl_xor(s, mask);
    float res = logit - m - __logf(s);
    if (act) out[(size_t)i * 40 + lane] = res;
}

extern "C" void kernel_launch(void* const* d_in, const int* in_sizes, int n_in,
                              void* d_out, int out_size, void* d_ws, size_t ws_size,
                              hipStream_t stream) {
    const float* x  = (const float*)d_in[0];
    const int*   e  = (const int*)d_in[1];
    const float* W1 = (const float*)d_in[2];
    const float* b1 = (const float*)d_in[3];
    const float* W2 = (const float*)d_in[4];
    const float* b2 = (const float*)d_in[5];
    float* out = (float*)d_out;

    const long long E = (long long)in_sizes[1] / 2;
    const int N = in_sizes[0] / 512;  // F_in = 512
    const long long M = E + N;
    const int nblk = (int)((M + CHUNK - 1) / CHUNK);

    char* w = (char*)d_ws;
    auto alloc = [&](size_t bytes) -> void* {
        void* p = (void*)w;
        w += (bytes + 255) & ~(size_t)255;
        return p;
    };
    int*  flag      = (int*)alloc(4);
    int*  gc        = (int*)alloc(NBMAX * 4);
    int*  bbase     = (int*)alloc((NBMAX + 1) * 4);
    int*  blockOffs = (int*)alloc((size_t)nblk * NBMAX * 4);
    int2* pair      = (int2*)alloc((size_t)M * 8);
    int*  rp        = (int*)alloc(((size_t)N + 1) * 4);
    int*  col       = (int*)alloc((size_t)M * 4);
    f16*  hA   = (f16*)alloc((size_t)N * HDIM * 2);
    f16*  hB   = (f16*)alloc((size_t)N * HDIM * 2);
    float* invA = (float*)alloc((size_t)N * 4);
    float* invB = (float*)alloc((size_t)N * 4);
    if ((size_t)(w - (char*)d_ws) > ws_size) return;

    k_flag<<<1, 64, 0, stream>>>(e, flag);
    k_zero<<<(NBMAX + 255) / 256, 256, 0, stream>>>(gc, NBMAX);
    k_hist<<<nblk, 256, 0, stream>>>(e, flag, gc, blockOffs, E, M);
    k_bscan<<<1, 256, 0, stream>>>(gc, bbase, rp, N);
    k_part<<<nblk, 256, 0, stream>>>(e, flag, bbase, blockOffs, pair, E, M);
    k_fine<<<NBMAX, 256, 0, stream>>>(pair, bbase, rp, col, N);

    k_gemm1<<<(N + 63) / 64, 256, 0, stream>>>(x, W1, b1, hA, invA, N);

    f16 *hin = hA, *hout = hB;
    float *iin = invA, *iout = invB;
    for (int l = 0; l < 32; ++l) {
        k_agnn<<<(N + 3) / 4, 256, 0, stream>>>(hin, iin, hout, iout, rp, col, N);
        f16* t = hin; hin = hout; hout = t;
        float* ti = iin; iin = iout; iout = ti;
    }
    k_gemm2<<<(N + 3) / 4, 256, 0, stream>>>(hin, W2, b2, out, N);
}